// Round 7
// baseline (241.535 us; speedup 1.0000x reference)
//
#include <hip/hip_runtime.h>

#define EMA_EPS 1e-12f
#define WTHR    1e-12f   // weight threshold: w_t below this cannot affect fp32 result
#define TS      32       // s-rows per block in the scan+norm kernel

typedef float v4f __attribute__((ext_vector_type(4)));

__device__ __forceinline__ float wave_reduce_sum(float v) {
    #pragma unroll
    for (int off = 32; off > 0; off >>= 1) v += __shfl_xor(v, off, 64);
    return v;
}

// Rows with index >= cut(alpha) have w_t = (1-a)a^t < WTHR -> contribute 0.
// IDENTICAL formula in K1 and K2 so the write-set and the guard-set match
// exactly (K1 never skips a row K2 reads, and never writes one it guards).
__device__ __forceinline__ int decay_cutoff(float oma, float l2a, int S) {
    int cut = S;
    if (oma > 0.0f && l2a < -1e-20f) {
        // log2(1e-12) = -39.863137
        float tc = (-39.863137f - __log2f(oma)) / l2a;
        if (tc < 0.0f)          cut = 0;
        else if (tc < (float)S) cut = (int)tc + 2;
    }
    return cut;
}

// ---------------------------------------------------------------------------
// K1: per-row mean/std (ddof=1) premultiplied by w_t = (1-a)*a^t, written as
// interleaved float2 {w*mean, w*sd}. Grid-strided over the COMPACTED index
// space [0, B*cut) so no wave is dispatched for a row past the decay cutoff.
// Normal (cached) loads on purpose: leaves these rows L3-resident for K2.
// ---------------------------------------------------------------------------
__global__ __launch_bounds__(256) void ema_stats_kernel(
    const float* __restrict__ x,
    float2* __restrict__ wms,
    const float* __restrict__ alpha_logit,
    int B, int S, int d4)
{
    const float alpha = 1.0f / (1.0f + __expf(-alpha_logit[0]));
    const float oma   = 1.0f - alpha;
    const float l2a   = __log2f(alpha);
    const int   cut   = decay_cutoff(oma, l2a, S);

    const int lane  = threadIdx.x & 63;
    const int gw    = (int)((blockIdx.x * blockDim.x + threadIdx.x) >> 6);
    const int nw    = (int)((gridDim.x * blockDim.x) >> 6);
    const int nwork = B * cut;            // rows that actually matter

    for (int k = gw; k < nwork; k += nw) {
        const int b   = k / cut;          // runtime div, once per row
        const int t   = k - b * cut;
        const int row = b * S + t;

        const float4* xr = (const float4*)x + (size_t)row * d4;
        float s = 0.f, sq = 0.f;
        for (int c = lane; c < d4; c += 64) {
            float4 a = xr[c];
            s  += a.x + a.y + a.z + a.w;
            sq += a.x*a.x + a.y*a.y + a.z*a.z + a.w*a.w;
        }
        s  = wave_reduce_sum(s);
        sq = wave_reduce_sum(sq);
        if (lane == 0) {
            const int n  = d4 * 4;
            float mean = s / (float)n;
            float var  = (sq - s * mean) / (float)(n - 1);
            float sd   = sqrtf(fmaxf(var, 0.0f));
            float w    = oma * exp2f((float)t * l2a);
            wms[row] = make_float2(w * mean, w * sd);
        }
    }
}

// ---------------------------------------------------------------------------
// K2: fused prefix-reduce + tile-scan + normalize. Block (b, tile) owns rows
// [s0, s0+TS). Phase A redundantly sums the weighted prefix over
// [0, min(s0, cut)) as ONE float4 stream over the interleaved pairs.
// Phase B: wave 0 scans mu in lanes 0-31 and sigma in lanes 32-63 (width-32
// shuffles), zero-guarded past the cutoff. Phase C: streaming normalize with
// non-temporal x loads (x dead after) and non-temporal y stores.
// ---------------------------------------------------------------------------
__global__ __launch_bounds__(256) void ema_scan_norm_kernel(
    const float* __restrict__ x,
    const float2* __restrict__ wms,
    const float* __restrict__ h, const float* __restrict__ alpha_logit,
    const float* __restrict__ gamma, const float* __restrict__ beta,
    float* __restrict__ out, int B, int S, int d4_shift)
{
    const int tiles = S / TS;
    const int b     = (int)blockIdx.x / tiles;
    const int tile  = (int)blockIdx.x % tiles;
    const int s0    = tile * TS;
    const int tid   = (int)threadIdx.x;
    const int d4    = 1 << d4_shift;
    const int D     = d4 << 2;

    const float alpha = 1.0f / (1.0f + __expf(-alpha_logit[0]));
    const float oma   = 1.0f - alpha;
    const float l2a   = __log2f(alpha);
    const int   cut   = decay_cutoff(oma, l2a, S);

    const float2* wb = wms + (size_t)b * S;

    __shared__ float sh_wm[4], sh_ws[4];
    __shared__ float sh_pm, sh_ps;
    __shared__ float sh_m[TS], sh_r[TS];

    // ---- Phase A: truncated weighted-prefix reduction over [0, min(s0,cut))
    //      One float4 stream = two {wm,ws} pairs per load.
    const int m0 = (s0 < cut) ? s0 : cut;
    const int nv = m0 >> 1;                    // float4 count (2 pairs each)
    const float4* w4 = (const float4*)wb;      // b*S even -> 16B aligned
    float lm = 0.f, ls = 0.f;
    for (int i = tid; i < nv; i += 256) {
        float4 v = w4[i];
        lm += v.x + v.z;
        ls += v.y + v.w;
    }
    if ((m0 & 1) && tid == 0) {                // odd tail pair
        float2 v = wb[m0 - 1];
        lm += v.x; ls += v.y;
    }
    lm = wave_reduce_sum(lm);
    ls = wave_reduce_sum(ls);
    if ((tid & 63) == 0) { sh_wm[tid >> 6] = lm; sh_ws[tid >> 6] = ls; }
    __syncthreads();
    if (tid == 0) {
        sh_pm = sh_wm[0] + sh_wm[1] + sh_wm[2] + sh_wm[3];
        sh_ps = sh_ws[0] + sh_ws[1] + sh_ws[2] + sh_ws[3];
    }
    __syncthreads();

    // ---- Phase B: wave 0 dual 32-lane scans (mu in lanes 0-31, sigma 32-63),
    //      zero-guarded past the decay cutoff (those rows were never written).
    if (tid < 64) {
        const int  r   = tid & 31;
        const bool isM = tid < 32;
        float v = 0.0f;
        if (s0 + r < cut) {
            float2 p = wb[s0 + r];
            v = isM ? p.x : p.y;
        }
        #pragma unroll
        for (int off = 1; off < 32; off <<= 1) {
            float tv = __shfl_up(v, off, 32);
            if (r >= off) v += tv;
        }
        const float base = isM ? (alpha * h[b*2 + 0] + sh_pm)
                               : (alpha * h[b*2 + 1] + sh_ps);
        const float run = base + v;
        if (isM) sh_m[r] = run;
        else     sh_r[r] = 1.0f / fmaxf(run, EMA_EPS);
        if (s0 + TS == S && r == 31) {
            float* h_new = out + (size_t)B * S * D;
            if (isM) h_new[b*2 + 0] = run;
            else     h_new[b*2 + 1] = fmaxf(run, EMA_EPS);
        }
    }
    __syncthreads();

    // ---- Phase C: streaming normalize; nt loads (x dead after) + nt stores.
    //      Loads/stores go through the native ext-vector type v4f —
    //      __builtin_nontemporal_* rejects HIP_vector_type (struct) pointers.
    const size_t base = (size_t)(b * S + s0) << d4_shift;
    const v4f* xb = (const v4f*)x + base;
    v4f*       yb = (v4f*)out + base;
    const float4* g4 = (const float4*)gamma;
    const float4* b4 = (const float4*)beta;
    const int n4 = TS << d4_shift;
    #pragma unroll 4
    for (int i = tid; i < n4; i += 256) {
        const int r = i >> d4_shift;
        const int c = i & (d4 - 1);
        const float m  = sh_m[r];
        const float rs = sh_r[r];
        float4 g  = g4[c];
        float4 bt = b4[c];
        v4f xv = __builtin_nontemporal_load(&xb[i]);
        v4f yv;
        yv.x = (xv.x - m) * rs * g.x + bt.x;
        yv.y = (xv.y - m) * rs * g.y + bt.y;
        yv.z = (xv.z - m) * rs * g.z + bt.z;
        yv.w = (xv.w - m) * rs * g.w + bt.w;
        __builtin_nontemporal_store(yv, &yb[i]);
    }
}

extern "C" void kernel_launch(void* const* d_in, const int* in_sizes, int n_in,
                              void* d_out, int out_size, void* d_ws, size_t ws_size,
                              hipStream_t stream) {
    const float* x           = (const float*)d_in[0];
    const float* h           = (const float*)d_in[1];
    const float* gamma       = (const float*)d_in[2];
    const float* beta        = (const float*)d_in[3];
    const float* alpha_logit = (const float*)d_in[4];
    float* out = (float*)d_out;

    const int D     = in_sizes[2];          // 512
    const int B     = in_sizes[1] / 2;      // 8
    const int total = in_sizes[0];          // B*S*D
    const int S     = total / (B * D);      // 8192
    const int d4    = D / 4;
    const int d4_shift = __builtin_ctz(d4);

    float2* wms = (float2*)d_ws;            // interleaved {w*mean, w*sd}

    // K1: weighted stats, grid-strided over compacted below-cutoff rows only.
    ema_stats_kernel<<<2048, 256, 0, stream>>>(x, wms, alpha_logit, B, S, d4);

    // K2: fused truncated-prefix + dual-scan + streaming normalize.
    ema_scan_norm_kernel<<<B * (S / TS), 256, 0, stream>>>(
        x, wms, h, alpha_logit, gamma, beta, out, B, S, d4_shift);
}